// Round 12
// baseline (39.416 us; speedup 1.0000x reference)
//
#include <hip/hip_runtime.h>
#include <hip/hip_bf16.h>

// ResidualRotationWarpLayer: out[b,y,x,c] = bilinear(images[b], H_b warp of (x,y))
// H_b = diag(fx,fy,1) * R(q) * diag(fx,fy,1)^-1
// B=32, H=512, W=512, C=3, fp32.
//
// R12: persistent row-loop. 2048 blocks (8/CU exactly); each block processes
// 8 consecutive rows of one image. Per-thread H (no thread0 serialization),
// double-buffered LDS staging -> ONE barrier per row, proven contiguous NT
// store path, R8 interior fast path + rcp, XCD swizzle (4 images/XCD).

#define IMG_H 512
#define IMG_W 512
#define IMG_C 3
#define NB    32

typedef float f32x4  __attribute__((ext_vector_type(4)));
typedef float f32x4u __attribute__((ext_vector_type(4), aligned(4)));
typedef float f32x2u __attribute__((ext_vector_type(2), aligned(4)));

__global__ __launch_bounds__(256) void warp_kernel(
    const float* __restrict__ images,
    const float* __restrict__ focal,
    const float* __restrict__ q,
    float* __restrict__ out)
{
    // --- XCD-aware remap: 2048 blocks = 8 XCDs * 256; each XCD owns 4 images
    const unsigned bid  = blockIdx.x;
    const unsigned xcd  = bid & 7u;
    const unsigned slot = bid >> 3;           // 0..255 within XCD
    const unsigned virt = xcd * 256u + slot;  // 0..2047
    const int b  = (int)(virt >> 6);          // 64 row-groups per image
    const int yg = (int)(virt & 63u) * 8;     // first of 8 rows

    const int tid = threadIdx.x;

    __shared__ float s_out[2][IMG_W * IMG_C];   // 2 * 1536 floats = 12 KB

    // --- per-thread homography (uniform scalar loads; no LDS, no barrier) ---
    float q0 = q[0], q1 = q[1], q2 = q[2], q3 = q[3];
    {
        float s = sqrtf(2.0f / (q0*q0 + q1*q1 + q2*q2 + q3*q3));
        q0 *= s; q1 *= s; q2 *= s; q3 *= s;
    }
    const float R00 = 1.0f - q2*q2 - q3*q3;
    const float R01 = q1*q2 - q3*q0;
    const float R02 = q1*q3 + q2*q0;
    const float R10 = q1*q2 + q3*q0;
    const float R11 = 1.0f - q1*q1 - q3*q3;
    const float R12 = q2*q3 - q1*q0;
    const float R20 = q1*q3 - q2*q0;
    const float R21 = q2*q3 + q1*q0;
    const float R22 = 1.0f - q1*q1 - q2*q2;
    const float d0 = focal[b*2 + 0];
    const float d1 = focal[b*2 + 1];

    const float h0 = (R00*d0)/d0;
    const float h1 = (R01*d0)/d1;
    const float h2 = (R02*d0);
    const float h3 = (R10*d1)/d0;
    const float h4 = (R11*d1)/d1;
    const float h5 = (R12*d1);
    const float h6 = R20/d0;
    const float h7 = R21/d1;
    const float h8 = R22;

    const float* __restrict__ img_b = images + (unsigned)b * (IMG_H * IMG_W * IMG_C);

    #define SAMPLE(PX, R1, R4, R7, A0, A1, A2) do {                            \
        const float xs = (float)(PX) - 256.0f;                                 \
        float p0 = fmaf(h0, xs, R1);                                           \
        float p1 = fmaf(h3, xs, R4);                                           \
        float p2 = fmaf(h6, xs, R7);                                           \
        float rp2 = __builtin_amdgcn_rcpf(p2);                                 \
        float xw = fmaf(p0, rp2, 256.0f);                                      \
        float yw = fmaf(p1, rp2, 256.0f);                                      \
        float x0f = floorf(xw), y0f = floorf(yw);                              \
        float wx = xw - x0f,   wy = yw - y0f;                                  \
        int x0 = (int)x0f, y0i = (int)y0f;                                     \
        bool interior = (x0 >= 0) & (y0i >= 0) &                               \
                        (x0 < IMG_W-1) & (y0i < IMG_H-1);                      \
        if (__all(interior)) {                                                 \
            /* fast path: no clamps/masks; 6-float pair load per corner row */ \
            const float* bpA = img_b + ((unsigned)y0i * IMG_W + (unsigned)x0) * 3u; \
            const float* bpB = bpA + IMG_W * 3u;                               \
            f32x4u vA0 = *reinterpret_cast<const f32x4u*>(bpA);                \
            f32x2u vA1 = *reinterpret_cast<const f32x2u*>(bpA + 4);            \
            f32x4u vB0 = *reinterpret_cast<const f32x4u*>(bpB);                \
            f32x2u vB1 = *reinterpret_cast<const f32x2u*>(bpB + 4);            \
            float w00 = (1.0f - wx) * (1.0f - wy);                             \
            float w01 = wx * (1.0f - wy);                                      \
            float w10 = (1.0f - wx) * wy;                                      \
            float w11 = wx * wy;                                               \
            A0 = vA0.x*w00 + vA0.w*w01 + vB0.x*w10 + vB0.w*w11;                \
            A1 = vA0.y*w00 + vA1.x*w01 + vB0.y*w10 + vB1.x*w11;                \
            A2 = vA0.z*w00 + vA1.y*w01 + vB0.z*w10 + vB1.y*w11;                \
        } else {                                                               \
            /* slow path: scalar clamped loads, masked weights */              \
            int x1 = x0 + 1, y1i = y0i + 1;                                    \
            bool vx0 = (x0 >= 0) & (x0 <= IMG_W-1);                            \
            bool vx1 = (x1 >= 0) & (x1 <= IMG_W-1);                            \
            bool vy0 = (y0i >= 0) & (y0i <= IMG_H-1);                          \
            bool vy1 = (y1i >= 0) & (y1i <= IMG_H-1);                          \
            unsigned xc0 = (unsigned)min(max(x0, 0), IMG_W-1);                 \
            unsigned xc1 = (unsigned)min(max(x1, 0), IMG_W-1);                 \
            unsigned yc0 = (unsigned)min(max(y0i, 0), IMG_H-1);                \
            unsigned yc1 = (unsigned)min(max(y1i, 0), IMG_H-1);                \
            const float* p00 = img_b + (yc0 * IMG_W + xc0) * IMG_C;            \
            const float* p01 = img_b + (yc0 * IMG_W + xc1) * IMG_C;            \
            const float* p10 = img_b + (yc1 * IMG_W + xc0) * IMG_C;            \
            const float* p11 = img_b + (yc1 * IMG_W + xc1) * IMG_C;            \
            float a00 = p00[0], a01 = p00[1], a02 = p00[2];                    \
            float b00 = p01[0], b01 = p01[1], b02 = p01[2];                    \
            float c00 = p10[0], c01 = p10[1], c02 = p10[2];                    \
            float d00 = p11[0], d01 = p11[1], d02 = p11[2];                    \
            float w00 = (vx0 & vy0) ? (1.0f - wx) * (1.0f - wy) : 0.0f;        \
            float w01 = (vx1 & vy0) ? wx * (1.0f - wy)          : 0.0f;        \
            float w10 = (vx0 & vy1) ? (1.0f - wx) * wy          : 0.0f;        \
            float w11 = (vx1 & vy1) ? wx * wy                   : 0.0f;        \
            A0 = a00*w00 + b00*w01 + c00*w10 + d00*w11;                        \
            A1 = a01*w00 + b01*w01 + c01*w10 + d01*w11;                        \
            A2 = a02*w00 + b02*w01 + c02*w10 + d02*w11;                        \
        }                                                                      \
    } while (0)

    #pragma unroll 2
    for (int i = 0; i < 8; ++i) {
        const int y = yg + i;
        const float ys = (float)y - 256.0f;
        const float r1 = fmaf(h1, ys, h2);
        const float r4 = fmaf(h4, ys, h5);
        const float r7 = fmaf(h7, ys, h8);

        float o0a, o1a, o2a, o0b, o1b, o2b;
        SAMPLE(tid,       r1, r4, r7, o0a, o1a, o2a);
        SAMPLE(tid + 256, r1, r4, r7, o0b, o1b, o2b);

        float* buf = s_out[i & 1];
        buf[tid*3 + 0] = o0a;
        buf[tid*3 + 1] = o1a;
        buf[tid*3 + 2] = o2a;
        buf[(tid + 256)*3 + 0] = o0b;
        buf[(tid + 256)*3 + 1] = o1b;
        buf[(tid + 256)*3 + 2] = o2b;
        __syncthreads();   // double-buffer: one barrier/row covers W->R and R->W(+2)

        f32x4* outp = reinterpret_cast<f32x4*>(
            out + ((unsigned)(b * IMG_H + y)) * (IMG_W * IMG_C));
        f32x4 v0 = *reinterpret_cast<const f32x4*>(&buf[tid * 4]);
        __builtin_nontemporal_store(v0, &outp[tid]);
        if (tid < 128) {
            f32x4 v1 = *reinterpret_cast<const f32x4*>(&buf[(256 + tid) * 4]);
            __builtin_nontemporal_store(v1, &outp[256 + tid]);
        }
    }
    #undef SAMPLE
}

extern "C" void kernel_launch(void* const* d_in, const int* in_sizes, int n_in,
                              void* d_out, int out_size, void* d_ws, size_t ws_size,
                              hipStream_t stream) {
    const float* images = (const float*)d_in[0];
    const float* focal  = (const float*)d_in[1];
    const float* q      = (const float*)d_in[2];
    float* out = (float*)d_out;

    dim3 grid(2048);    // 8 XCDs * 256 blocks; each block does 8 rows
    dim3 block(256);
    warp_kernel<<<grid, block, 0, stream>>>(images, focal, q, out);
}

// Round 13
// 36.066 us; speedup vs baseline: 1.0929x; 1.0929x over previous
//
#include <hip/hip_runtime.h>
#include <hip/hip_bf16.h>

// ResidualRotationWarpLayer: out[b,y,x,c] = bilinear(images[b], H_b warp of (x,y))
// H_b = diag(fx,fy,1) * R(q) * diag(fx,fy,1)^-1
// B=32, H=512, W=512, C=3, fp32.
//
// R13: paired-pixel gather. Thread samples pixels (2t, 2t+1); their corner
// rows share one 9-float load span (x4+x4+dword) -> gather lines ~halved.
// Wave-uniform fast path needs y0 equal + x0 delta in {0,1} + interior.
// Per-thread H, rcp, 16384 blocks, XCD swizzle, LDS-staged NT stores.

#define IMG_H 512
#define IMG_W 512
#define IMG_C 3
#define NB    32

typedef float f32x4  __attribute__((ext_vector_type(4)));
typedef float f32x4u __attribute__((ext_vector_type(4), aligned(4)));

__global__ __launch_bounds__(256) void warp_kernel(
    const float* __restrict__ images,
    const float* __restrict__ focal,
    const float* __restrict__ q,
    float* __restrict__ out)
{
    // --- XCD-aware remap: 16384 blocks = 8 XCDs * 2048; each XCD owns 4 images
    const unsigned bid  = blockIdx.x;
    const unsigned xcd  = bid & 7u;
    const unsigned slot = bid >> 3;
    const unsigned virt = xcd * 2048u + slot;
    const int b = (int)(virt >> 9);      // 512 rows per image
    const int y = (int)(virt & 511u);

    const int tid = threadIdx.x;

    __shared__ float s_out[IMG_W * IMG_C];   // 1536 floats = 6 KB

    // --- per-thread homography (uniform scalar loads; no barrier) ---
    float q0 = q[0], q1 = q[1], q2 = q[2], q3 = q[3];
    {
        float s = sqrtf(2.0f / (q0*q0 + q1*q1 + q2*q2 + q3*q3));
        q0 *= s; q1 *= s; q2 *= s; q3 *= s;
    }
    const float R00 = 1.0f - q2*q2 - q3*q3;
    const float R01 = q1*q2 - q3*q0;
    const float R02 = q1*q3 + q2*q0;
    const float R10 = q1*q2 + q3*q0;
    const float R11 = 1.0f - q1*q1 - q3*q3;
    const float R12 = q2*q3 - q1*q0;
    const float R20 = q1*q3 - q2*q0;
    const float R21 = q2*q3 + q1*q0;
    const float R22 = 1.0f - q1*q1 - q2*q2;
    const float d0 = focal[b*2 + 0];
    const float d1 = focal[b*2 + 1];

    const float h0 = (R00*d0)/d0;
    const float h1 = (R01*d0)/d1;
    const float h2 = (R02*d0);
    const float h3 = (R10*d1)/d0;
    const float h4 = (R11*d1)/d1;
    const float h5 = (R12*d1);
    const float h6 = R20/d0;
    const float h7 = R21/d1;
    const float h8 = R22;

    const float ys = (float)y - 256.0f;
    const float r1 = h1*ys + h2;
    const float r4 = h4*ys + h5;
    const float r7 = h7*ys + h8;

    const float* __restrict__ img_b = images + (unsigned)b * (IMG_H * IMG_W * IMG_C);

    // ---- projective transform for the pixel pair ----
    const int px = tid * 2;
    float xwa, ywa, xwb, ywb;
    {
        const float xsa = (float)px - 256.0f;
        float p0 = fmaf(h0, xsa, r1);
        float p1 = fmaf(h3, xsa, r4);
        float p2 = fmaf(h6, xsa, r7);
        float rp = __builtin_amdgcn_rcpf(p2);
        xwa = fmaf(p0, rp, 256.0f);
        ywa = fmaf(p1, rp, 256.0f);
        const float xsb = xsa + 1.0f;
        float p0b = fmaf(h0, xsb, r1);
        float p1b = fmaf(h3, xsb, r4);
        float p2b = fmaf(h6, xsb, r7);
        float rpb = __builtin_amdgcn_rcpf(p2b);
        xwb = fmaf(p0b, rpb, 256.0f);
        ywb = fmaf(p1b, rpb, 256.0f);
    }

    float x0fa = floorf(xwa), y0fa = floorf(ywa);
    float x0fb = floorf(xwb), y0fb = floorf(ywb);
    float wxa = xwa - x0fa, wya = ywa - y0fa;
    float wxb = xwb - x0fb, wyb = ywb - y0fb;
    int x0a = (int)x0fa, y0a = (int)y0fa;
    int x0b = (int)x0fb, y0b = (int)y0fb;

    bool interior_a = (x0a >= 0) & (y0a >= 0) & (x0a < IMG_W-1) & (y0a < IMG_H-1);
    bool interior_b = (x0b >= 0) & (y0b >= 0) & (x0b < IMG_W-1) & (y0b < IMG_H-1);
    int  dx = x0b - x0a;
    bool pairable = interior_a & interior_b & (y0b == y0a) & ((dx == 0) | (dx == 1));

    float o0a, o1a, o2a, o0b, o1b, o2b;

    if (__all(pairable)) {
        // shared 9-float span per corner row: cols x0a..x0a+2
        const bool dx1 = (dx == 1);
        const float* bpA = img_b + ((unsigned)y0a * IMG_W + (unsigned)x0a) * 3u;
        const float* bpB = bpA + IMG_W * 3u;
        f32x4u uA0 = *reinterpret_cast<const f32x4u*>(bpA);       // f0..f3
        f32x4u uA1 = *reinterpret_cast<const f32x4u*>(bpA + 4);   // f4..f7
        float  fA8 = *(bpA + (dx1 ? 8 : 0));                      // f8 (safe addr)
        f32x4u uB0 = *reinterpret_cast<const f32x4u*>(bpB);
        f32x4u uB1 = *reinterpret_cast<const f32x4u*>(bpB + 4);
        float  fB8 = *(bpB + (dx1 ? 8 : 0));

        // pixel a weights
        float w00a = (1.0f - wxa) * (1.0f - wya);
        float w01a = wxa * (1.0f - wya);
        float w10a = (1.0f - wxa) * wya;
        float w11a = wxa * wya;
        o0a = uA0.x*w00a + uA0.w*w01a + uB0.x*w10a + uB0.w*w11a;
        o1a = uA0.y*w00a + uA1.x*w01a + uB0.y*w10a + uB1.x*w11a;
        o2a = uA0.z*w00a + uA1.y*w01a + uB0.z*w10a + uB1.y*w11a;

        // pixel b corner floats: shift by 3 when dx1
        float c0A0 = dx1 ? uA0.w : uA0.x;
        float c0A1 = dx1 ? uA1.x : uA0.y;
        float c0A2 = dx1 ? uA1.y : uA0.z;
        float c1A0 = dx1 ? uA1.z : uA0.w;
        float c1A1 = dx1 ? uA1.w : uA1.x;
        float c1A2 = dx1 ? fA8   : uA1.y;
        float c0B0 = dx1 ? uB0.w : uB0.x;
        float c0B1 = dx1 ? uB1.x : uB0.y;
        float c0B2 = dx1 ? uB1.y : uB0.z;
        float c1B0 = dx1 ? uB1.z : uB0.w;
        float c1B1 = dx1 ? uB1.w : uB1.x;
        float c1B2 = dx1 ? fB8   : uB1.y;

        float w00b = (1.0f - wxb) * (1.0f - wyb);
        float w01b = wxb * (1.0f - wyb);
        float w10b = (1.0f - wxb) * wyb;
        float w11b = wxb * wyb;
        o0b = c0A0*w00b + c1A0*w01b + c0B0*w10b + c1B0*w11b;
        o1b = c0A1*w00b + c1A1*w01b + c0B1*w10b + c1B1*w11b;
        o2b = c0A2*w00b + c1A2*w01b + c0B2*w10b + c1B2*w11b;
    } else {
        // slow path: per-pixel scalar clamped loads, masked weights
        #define SAMPLE_SLOW(X0, Y0, WX, WY, A0, A1, A2) do {                   \
            int x1 = (X0) + 1, y1i = (Y0) + 1;                                 \
            bool vx0 = ((X0) >= 0) & ((X0) <= IMG_W-1);                        \
            bool vx1 = (x1 >= 0) & (x1 <= IMG_W-1);                            \
            bool vy0 = ((Y0) >= 0) & ((Y0) <= IMG_H-1);                        \
            bool vy1 = (y1i >= 0) & (y1i <= IMG_H-1);                          \
            unsigned xc0 = (unsigned)min(max((X0), 0), IMG_W-1);               \
            unsigned xc1 = (unsigned)min(max(x1, 0), IMG_W-1);                 \
            unsigned yc0 = (unsigned)min(max((Y0), 0), IMG_H-1);               \
            unsigned yc1 = (unsigned)min(max(y1i, 0), IMG_H-1);                \
            const float* p00 = img_b + (yc0 * IMG_W + xc0) * IMG_C;            \
            const float* p01 = img_b + (yc0 * IMG_W + xc1) * IMG_C;            \
            const float* p10 = img_b + (yc1 * IMG_W + xc0) * IMG_C;            \
            const float* p11 = img_b + (yc1 * IMG_W + xc1) * IMG_C;            \
            float a00 = p00[0], a01 = p00[1], a02 = p00[2];                    \
            float b00 = p01[0], b01 = p01[1], b02 = p01[2];                    \
            float c00 = p10[0], c01 = p10[1], c02 = p10[2];                    \
            float d00 = p11[0], d01 = p11[1], d02 = p11[2];                    \
            float w00 = (vx0 & vy0) ? (1.0f - (WX)) * (1.0f - (WY)) : 0.0f;    \
            float w01 = (vx1 & vy0) ? (WX) * (1.0f - (WY))          : 0.0f;    \
            float w10 = (vx0 & vy1) ? (1.0f - (WX)) * (WY)          : 0.0f;    \
            float w11 = (vx1 & vy1) ? (WX) * (WY)                   : 0.0f;    \
            A0 = a00*w00 + b00*w01 + c00*w10 + d00*w11;                        \
            A1 = a01*w00 + b01*w01 + c01*w10 + d01*w11;                        \
            A2 = a02*w00 + b02*w01 + c02*w10 + d02*w11;                        \
        } while (0)
        SAMPLE_SLOW(x0a, y0a, wxa, wya, o0a, o1a, o2a);
        SAMPLE_SLOW(x0b, y0b, wxb, wyb, o0b, o1b, o2b);
        #undef SAMPLE_SLOW
    }

    // stage through LDS for coalesced, vectorized NT stores (proven path)
    s_out[px*3 + 0] = o0a;
    s_out[px*3 + 1] = o1a;
    s_out[px*3 + 2] = o2a;
    s_out[px*3 + 3] = o0b;
    s_out[px*3 + 4] = o1b;
    s_out[px*3 + 5] = o2b;
    __syncthreads();

    // 512 px * 3 ch = 1536 floats = 384 float4 per row
    f32x4* outp = reinterpret_cast<f32x4*>(
        out + ((unsigned)(b * IMG_H + y)) * (IMG_W * IMG_C));
    f32x4 v0 = *reinterpret_cast<const f32x4*>(&s_out[tid * 4]);
    __builtin_nontemporal_store(v0, &outp[tid]);
    if (tid < 128) {
        f32x4 v1 = *reinterpret_cast<const f32x4*>(&s_out[(256 + tid) * 4]);
        __builtin_nontemporal_store(v1, &outp[256 + tid]);
    }
}

extern "C" void kernel_launch(void* const* d_in, const int* in_sizes, int n_in,
                              void* d_out, int out_size, void* d_ws, size_t ws_size,
                              hipStream_t stream) {
    const float* images = (const float*)d_in[0];
    const float* focal  = (const float*)d_in[1];
    const float* q      = (const float*)d_in[2];
    float* out = (float*)d_out;

    dim3 grid(16384);   // H * B = 512 * 32 rows, one row per block
    dim3 block(256);
    warp_kernel<<<grid, block, 0, stream>>>(images, focal, q, out);
}